// Round 1
// baseline (2354.658 us; speedup 1.0000x reference)
//
#include <hip/hip_runtime.h>
#include <math.h>

#define B_  2
#define S_  2048
#define E_  1024
#define H_  16
#define D_  64
#define BS_ (B_*S_)   // 4096 rows
#define HD_ (H_*D_)   // 1024
#define LN_EPS 1e-5f

#define DOT4(a,b) ((a).x*(b).x + (a).y*(b).y + (a).z*(b).z + (a).w*(b).w)

// ---------------------------------------------------------------------------
// GEMM: C[M,N] = A[M,K] @ W[K,N] + bias[N]   (fp32, 64x64 tile, 4x4 microtile)
// M%64==0, N%64==0, K%16==0 required (holds: 4096/1024/1024).
// ---------------------------------------------------------------------------
__global__ __launch_bounds__(256) void gemm_bias(
    const float* __restrict__ A, const float* __restrict__ W,
    const float* __restrict__ bias, float* __restrict__ C,
    int M, int N, int K)
{
  __shared__ float As[16][68];   // k-major, padded (+4 keeps 16B row align)
  __shared__ float Bs[16][68];
  const int t  = threadIdx.x;
  const int tx = t & 15, ty = t >> 4;
  const int m0 = blockIdx.y * 64, n0 = blockIdx.x * 64;
  const int ar = t >> 2, ac = (t & 3) << 2;   // A tile load: 64 rows x 16 k
  const int br = t >> 4, bc = (t & 15) << 2;  // B tile load: 16 k x 64 n
  float acc[4][4] = {};

  for (int k0 = 0; k0 < K; k0 += 16) {
    float4 av = *(const float4*)&A[(size_t)(m0 + ar) * K + k0 + ac];
    float4 bv = *(const float4*)&W[(size_t)(k0 + br) * N + n0 + bc];
    __syncthreads();
    As[ac + 0][ar] = av.x;
    As[ac + 1][ar] = av.y;
    As[ac + 2][ar] = av.z;
    As[ac + 3][ar] = av.w;
    *(float4*)&Bs[br][bc] = bv;
    __syncthreads();
#pragma unroll
    for (int kk = 0; kk < 16; ++kk) {
      float4 a4 = *(const float4*)&As[kk][ty << 2];
      float4 b4 = *(const float4*)&Bs[kk][tx << 2];
      acc[0][0] += a4.x*b4.x; acc[0][1] += a4.x*b4.y; acc[0][2] += a4.x*b4.z; acc[0][3] += a4.x*b4.w;
      acc[1][0] += a4.y*b4.x; acc[1][1] += a4.y*b4.y; acc[1][2] += a4.y*b4.z; acc[1][3] += a4.y*b4.w;
      acc[2][0] += a4.z*b4.x; acc[2][1] += a4.z*b4.y; acc[2][2] += a4.z*b4.z; acc[2][3] += a4.z*b4.w;
      acc[3][0] += a4.w*b4.x; acc[3][1] += a4.w*b4.y; acc[3][2] += a4.w*b4.z; acc[3][3] += a4.w*b4.w;
    }
  }

  float4 bb = *(const float4*)&bias[n0 + (tx << 2)];
#pragma unroll
  for (int i = 0; i < 4; ++i) {
    float4 o;
    o.x = acc[i][0] + bb.x; o.y = acc[i][1] + bb.y;
    o.z = acc[i][2] + bb.z; o.w = acc[i][3] + bb.w;
    *(float4*)&C[(size_t)(m0 + (ty << 2) + i) * N + n0 + (tx << 2)] = o;
  }
}

// ---------------------------------------------------------------------------
// Attention: grid (S/32, B*H). Per block: 32 q-rows.
// Pass 1: online (m,l) over K-chunks of 64. Pass 2: recompute scores, write
// normalized attn (exactly once incl. zeros for masked region), accumulate PV.
// ctx[b,s,h,d] <- sum_j attn * V.  Q scaled by 1/sqrt(D) at load.
// Score columns per lane: col = tx + 16*j (keeps K LDS reads <=2-way conflicts)
// ---------------------------------------------------------------------------
__global__ __launch_bounds__(256) void attn_kernel(
    const float* __restrict__ qh, const float* __restrict__ kh,
    const float* __restrict__ vh, float* __restrict__ attn,
    float* __restrict__ ctx, const int* __restrict__ pmask)
{
  __shared__ float Qs[32][68];
  __shared__ float Ks[64][68];
  __shared__ float Vs[64][68];
  __shared__ float Ps[32][68];

  const int t  = threadIdx.x;
  const int tx = t & 15, ty = t >> 4;
  const int r0 = ty << 1;          // 2 rows per thread
  const int c0 = tx << 2;          // contiguous 4 cols (PV dims / zero-fill)
  const int q0 = blockIdx.x * 32;
  const int bh = blockIdx.y;
  const int b  = bh >> 4, h = bh & 15;
  const int isM  = pmask[0];
  const int kend = isM ? ((q0 & ~63) + 64) : S_;

  const float* qbase = qh + ((size_t)(b * S_ + q0) * H_ + h) * D_;
  const float* kbase = kh + ((size_t)(b * S_) * H_ + h) * D_;
  const float* vbase = vh + ((size_t)(b * S_) * H_ + h) * D_;

  // load Q tile (scaled by 1/sqrt(D))
#pragma unroll
  for (int i = 0; i < 2; ++i) {
    int f4 = t + i * 256;
    int r = f4 >> 4, c = (f4 & 15) << 2;
    float4 v = *(const float4*)&qbase[(size_t)r * HD_ + c];
    v.x *= 0.125f; v.y *= 0.125f; v.z *= 0.125f; v.w *= 0.125f;
    *(float4*)&Qs[r][c] = v;
  }

  float m[2] = {-1e30f, -1e30f};
  float l[2] = {0.f, 0.f};

  // ---------------- pass 1: stats ----------------
  for (int kc = 0; kc < kend; kc += 64) {
    __syncthreads();
#pragma unroll
    for (int i = 0; i < 4; ++i) {
      int f4 = t + i * 256;
      int r = f4 >> 4, c = (f4 & 15) << 2;
      *(float4*)&Ks[r][c] = *(const float4*)&kbase[(size_t)(kc + r) * HD_ + c];
    }
    __syncthreads();

    float s[2][4] = {};
#pragma unroll
    for (int d = 0; d < 64; d += 4) {
      float4 qa = *(const float4*)&Qs[r0 + 0][d];
      float4 qb = *(const float4*)&Qs[r0 + 1][d];
      float4 k0 = *(const float4*)&Ks[tx +  0][d];
      float4 k1 = *(const float4*)&Ks[tx + 16][d];
      float4 k2 = *(const float4*)&Ks[tx + 32][d];
      float4 k3 = *(const float4*)&Ks[tx + 48][d];
      s[0][0] += DOT4(qa,k0); s[0][1] += DOT4(qa,k1); s[0][2] += DOT4(qa,k2); s[0][3] += DOT4(qa,k3);
      s[1][0] += DOT4(qb,k0); s[1][1] += DOT4(qb,k1); s[1][2] += DOT4(qb,k2); s[1][3] += DOT4(qb,k3);
    }
    if (isM && (kc + 64 > q0)) {
#pragma unroll
      for (int i = 0; i < 2; ++i)
#pragma unroll
        for (int j = 0; j < 4; ++j)
          if (kc + tx + 16 * j > q0 + r0 + i) s[i][j] = -1e30f;
    }
#pragma unroll
    for (int i = 0; i < 2; ++i) {
      float cm = fmaxf(fmaxf(s[i][0], s[i][1]), fmaxf(s[i][2], s[i][3]));
      cm = fmaxf(cm, __shfl_xor(cm, 1, 16));
      cm = fmaxf(cm, __shfl_xor(cm, 2, 16));
      cm = fmaxf(cm, __shfl_xor(cm, 4, 16));
      cm = fmaxf(cm, __shfl_xor(cm, 8, 16));
      float mn = fmaxf(m[i], cm);
      float cs = __expf(s[i][0] - mn) + __expf(s[i][1] - mn) +
                 __expf(s[i][2] - mn) + __expf(s[i][3] - mn);
      cs += __shfl_xor(cs, 1, 16);
      cs += __shfl_xor(cs, 2, 16);
      cs += __shfl_xor(cs, 4, 16);
      cs += __shfl_xor(cs, 8, 16);
      l[i] = l[i] * __expf(m[i] - mn) + cs;
      m[i] = mn;
    }
  }
  float invl[2] = {1.f / l[0], 1.f / l[1]};

  // ---------------- pass 2: attn write + PV ----------------
  float o[2][4] = {};
  for (int kc = 0; kc < kend; kc += 64) {
    __syncthreads();
#pragma unroll
    for (int i = 0; i < 4; ++i) {
      int f4 = t + i * 256;
      int r = f4 >> 4, c = (f4 & 15) << 2;
      *(float4*)&Ks[r][c] = *(const float4*)&kbase[(size_t)(kc + r) * HD_ + c];
      *(float4*)&Vs[r][c] = *(const float4*)&vbase[(size_t)(kc + r) * HD_ + c];
    }
    __syncthreads();

    float s[2][4] = {};
#pragma unroll
    for (int d = 0; d < 64; d += 4) {
      float4 qa = *(const float4*)&Qs[r0 + 0][d];
      float4 qb = *(const float4*)&Qs[r0 + 1][d];
      float4 k0 = *(const float4*)&Ks[tx +  0][d];
      float4 k1 = *(const float4*)&Ks[tx + 16][d];
      float4 k2 = *(const float4*)&Ks[tx + 32][d];
      float4 k3 = *(const float4*)&Ks[tx + 48][d];
      s[0][0] += DOT4(qa,k0); s[0][1] += DOT4(qa,k1); s[0][2] += DOT4(qa,k2); s[0][3] += DOT4(qa,k3);
      s[1][0] += DOT4(qb,k0); s[1][1] += DOT4(qb,k1); s[1][2] += DOT4(qb,k2); s[1][3] += DOT4(qb,k3);
    }
    if (isM && (kc + 64 > q0)) {
#pragma unroll
      for (int i = 0; i < 2; ++i)
#pragma unroll
        for (int j = 0; j < 4; ++j)
          if (kc + tx + 16 * j > q0 + r0 + i) s[i][j] = -1e30f;
    }

    float* abase = attn + ((size_t)bh * S_ + (q0 + r0)) * S_ + kc;
#pragma unroll
    for (int i = 0; i < 2; ++i) {
      float p0 = __expf(s[i][0] - m[i]) * invl[i];
      float p1 = __expf(s[i][1] - m[i]) * invl[i];
      float p2 = __expf(s[i][2] - m[i]) * invl[i];
      float p3 = __expf(s[i][3] - m[i]) * invl[i];
      float* ar = abase + (size_t)i * S_;
      ar[tx]      = p0; ar[tx + 16] = p1; ar[tx + 32] = p2; ar[tx + 48] = p3;
      Ps[r0 + i][tx]      = p0; Ps[r0 + i][tx + 16] = p1;
      Ps[r0 + i][tx + 32] = p2; Ps[r0 + i][tx + 48] = p3;
    }
    __syncthreads();

#pragma unroll
    for (int jc = 0; jc < 64; jc += 4) {
      float4 pa = *(const float4*)&Ps[r0 + 0][jc];
      float4 pb = *(const float4*)&Ps[r0 + 1][jc];
      float4 v0 = *(const float4*)&Vs[jc + 0][c0];
      float4 v1 = *(const float4*)&Vs[jc + 1][c0];
      float4 v2 = *(const float4*)&Vs[jc + 2][c0];
      float4 v3 = *(const float4*)&Vs[jc + 3][c0];
      o[0][0] += pa.x*v0.x + pa.y*v1.x + pa.z*v2.x + pa.w*v3.x;
      o[0][1] += pa.x*v0.y + pa.y*v1.y + pa.z*v2.y + pa.w*v3.y;
      o[0][2] += pa.x*v0.z + pa.y*v1.z + pa.z*v2.z + pa.w*v3.z;
      o[0][3] += pa.x*v0.w + pa.y*v1.w + pa.z*v2.w + pa.w*v3.w;
      o[1][0] += pb.x*v0.x + pb.y*v1.x + pb.z*v2.x + pb.w*v3.x;
      o[1][1] += pb.x*v0.y + pb.y*v1.y + pb.z*v2.y + pb.w*v3.y;
      o[1][2] += pb.x*v0.z + pb.y*v1.z + pb.z*v2.z + pb.w*v3.z;
      o[1][3] += pb.x*v0.w + pb.y*v1.w + pb.z*v2.w + pb.w*v3.w;
    }
  }

  // zero-fill the fully-masked tail (d_out is poisoned 0xAA each launch)
  if (kend < S_) {
    float4 z; z.x = 0.f; z.y = 0.f; z.z = 0.f; z.w = 0.f;
    for (int kc = kend; kc < S_; kc += 64) {
      float* ar = attn + ((size_t)bh * S_ + (q0 + r0)) * S_ + kc + c0;
      *(float4*)(ar)      = z;
      *(float4*)(ar + S_) = z;
    }
  }

  // store O tile to ctx[b, s, h, d]
#pragma unroll
  for (int i = 0; i < 2; ++i) {
    float4 ov;
    ov.x = o[i][0]; ov.y = o[i][1]; ov.z = o[i][2]; ov.w = o[i][3];
    *(float4*)&ctx[((size_t)(b * S_ + q0 + r0 + i) * H_ + h) * D_ + c0] = ov;
  }
}

// ---------------------------------------------------------------------------
// In-place residual + LayerNorm over last dim (1024). One block per row.
// ---------------------------------------------------------------------------
__global__ __launch_bounds__(256) void ln_kernel(
    float* __restrict__ y, const float* __restrict__ resid)
{
  __shared__ float red[8];
  const int row = blockIdx.x, t = threadIdx.x;
  const size_t base = (size_t)row * 1024 + (t << 2);
  float4 x = *(float4*)&y[base];
  float4 r = *(const float4*)&resid[base];
  x.x += r.x; x.y += r.y; x.z += r.z; x.w += r.w;
  float sum = x.x + x.y + x.z + x.w;
  float ss  = x.x*x.x + x.y*x.y + x.z*x.z + x.w*x.w;
#pragma unroll
  for (int off = 1; off < 64; off <<= 1) {
    sum += __shfl_xor(sum, off);
    ss  += __shfl_xor(ss,  off);
  }
  const int wid = t >> 6;
  if ((t & 63) == 0) { red[wid] = sum; red[4 + wid] = ss; }
  __syncthreads();
  sum = red[0] + red[1] + red[2] + red[3];
  ss  = red[4] + red[5] + red[6] + red[7];
  const float mu  = sum * (1.f / 1024.f);
  const float var = ss * (1.f / 1024.f) - mu * mu;
  const float rs  = rsqrtf(var + LN_EPS);
  x.x = (x.x - mu) * rs; x.y = (x.y - mu) * rs;
  x.z = (x.z - mu) * rs; x.w = (x.w - mu) * rs;
  *(float4*)&y[base] = x;
}

// ---------------------------------------------------------------------------
extern "C" void kernel_launch(void* const* d_in, const int* in_sizes, int n_in,
                              void* d_out, int out_size, void* d_ws, size_t ws_size,
                              hipStream_t stream) {
  const float* q    = (const float*)d_in[0];
  const float* k    = (const float*)d_in[1];
  const float* v    = (const float*)d_in[2];
  const float* Wq   = (const float*)d_in[3];
  const float* bq   = (const float*)d_in[4];
  const float* Wk   = (const float*)d_in[5];
  const float* bk   = (const float*)d_in[6];
  const float* Wv   = (const float*)d_in[7];
  const float* bv   = (const float*)d_in[8];
  const float* Wo   = (const float*)d_in[9];
  const float* bo   = (const float*)d_in[10];
  const int*   mask = (const int*)d_in[11];

  float* outs = (float*)d_out;                         // [B*S, E]
  float* attn = outs + (size_t)BS_ * E_;               // [B, H, S, S]

  float* qh  = (float*)d_ws;                           // [B*S, H*D]
  float* kh  = qh  + (size_t)BS_ * HD_;
  float* vh  = kh  + (size_t)BS_ * HD_;
  float* ctx = vh  + (size_t)BS_ * HD_;

  const dim3 gg(HD_ / 64, BS_ / 64);                   // (16, 64)
  gemm_bias<<<gg, 256, 0, stream>>>(q, Wq, bq, qh, BS_, HD_, E_);
  gemm_bias<<<gg, 256, 0, stream>>>(k, Wk, bk, kh, BS_, HD_, E_);
  gemm_bias<<<gg, 256, 0, stream>>>(v, Wv, bv, vh, BS_, HD_, E_);

  attn_kernel<<<dim3(S_ / 32, B_ * H_), 256, 0, stream>>>(qh, kh, vh, attn, ctx, mask);

  gemm_bias<<<dim3(E_ / 64, BS_ / 64), 256, 0, stream>>>(ctx, Wo, bo, outs, BS_, E_, HD_);
  ln_kernel<<<BS_, 256, 0, stream>>>(outs, q);
}

// Round 2
// 1191.600 us; speedup vs baseline: 1.9760x; 1.9760x over previous
//
#include <hip/hip_runtime.h>
#include <math.h>

#define B_  2
#define S_  2048
#define E_  1024
#define H_  16
#define D_  64
#define BS_ (B_*S_)   // 4096 rows
#define HD_ (H_*D_)   // 1024
#define LN_EPS 1e-5f

typedef __bf16 bf16x8 __attribute__((ext_vector_type(8)));
typedef float  f32x4  __attribute__((ext_vector_type(4)));

__device__ __forceinline__ unsigned short f2bf(float x) {
  union { float f; unsigned int u; } v; v.f = x;
  unsigned int r = (v.u + 0x7FFFu + ((v.u >> 16) & 1u)) >> 16;  // RNE
  return (unsigned short)r;
}

// ---------------------------------------------------------------------------
// GEMM: C = A[M,K] @ W[K,N] + bias (fp32 compute, 64x64 tile, 4x4 microtile).
// MODE 0: fp32 C[M,N].
// MODE 1: bf16 out, head-major [b,h,s,d], value scaled by `scale`.
// MODE 2: bf16 out, transposed head-major [b,h,d,s]  (for V).
// ---------------------------------------------------------------------------
template<int MODE>
__global__ __launch_bounds__(256) void gemm_bias_k(
    const float* __restrict__ A, const float* __restrict__ W,
    const float* __restrict__ bias, float* __restrict__ Cf,
    unsigned short* __restrict__ Cb, int M, int N, int K, float scale)
{
  __shared__ float As[16][68];   // k-major, padded
  __shared__ float Bs[16][68];
  const int t  = threadIdx.x;
  const int tx = t & 15, ty = t >> 4;
  const int m0 = blockIdx.y * 64, n0 = blockIdx.x * 64;
  const int ar = t >> 2, ac = (t & 3) << 2;
  const int br = t >> 4, bc = (t & 15) << 2;
  float acc[4][4] = {};

  for (int k0 = 0; k0 < K; k0 += 16) {
    float4 av = *(const float4*)&A[(size_t)(m0 + ar) * K + k0 + ac];
    float4 bv = *(const float4*)&W[(size_t)(k0 + br) * N + n0 + bc];
    __syncthreads();
    As[ac + 0][ar] = av.x;
    As[ac + 1][ar] = av.y;
    As[ac + 2][ar] = av.z;
    As[ac + 3][ar] = av.w;
    *(float4*)&Bs[br][bc] = bv;
    __syncthreads();
#pragma unroll
    for (int kk = 0; kk < 16; ++kk) {
      float4 a4 = *(const float4*)&As[kk][ty << 2];
      float4 b4 = *(const float4*)&Bs[kk][tx << 2];
      acc[0][0] += a4.x*b4.x; acc[0][1] += a4.x*b4.y; acc[0][2] += a4.x*b4.z; acc[0][3] += a4.x*b4.w;
      acc[1][0] += a4.y*b4.x; acc[1][1] += a4.y*b4.y; acc[1][2] += a4.y*b4.z; acc[1][3] += a4.y*b4.w;
      acc[2][0] += a4.z*b4.x; acc[2][1] += a4.z*b4.y; acc[2][2] += a4.z*b4.z; acc[2][3] += a4.z*b4.w;
      acc[3][0] += a4.w*b4.x; acc[3][1] += a4.w*b4.y; acc[3][2] += a4.w*b4.z; acc[3][3] += a4.w*b4.w;
    }
  }

  float4 bb = *(const float4*)&bias[n0 + (tx << 2)];

  if (MODE == 0) {
#pragma unroll
    for (int i = 0; i < 4; ++i) {
      float4 o;
      o.x = acc[i][0] + bb.x; o.y = acc[i][1] + bb.y;
      o.z = acc[i][2] + bb.z; o.w = acc[i][3] + bb.w;
      *(float4*)&Cf[(size_t)(m0 + (ty << 2) + i) * N + n0 + (tx << 2)] = o;
    }
  } else if (MODE == 1) {
    const int h  = n0 >> 6;
    const int d0 = (n0 & 63) + (tx << 2);
#pragma unroll
    for (int i = 0; i < 4; ++i) {
      int m = m0 + (ty << 2) + i;
      int b = m >> 11, s = m & (S_ - 1);
      ushort4 o;
      o.x = f2bf((acc[i][0] + bb.x) * scale);
      o.y = f2bf((acc[i][1] + bb.y) * scale);
      o.z = f2bf((acc[i][2] + bb.z) * scale);
      o.w = f2bf((acc[i][3] + bb.w) * scale);
      *(ushort4*)&Cb[(((size_t)(b * H_ + h)) * S_ + s) * 64 + d0] = o;
    }
  } else {
    const int h  = n0 >> 6;
    const int d0 = (n0 & 63) + (tx << 2);
#pragma unroll
    for (int i = 0; i < 4; ++i) {
      int m = m0 + (ty << 2) + i;
      int b = m >> 11, s = m & (S_ - 1);
      size_t base = ((size_t)(b * H_ + h)) * 64;
      Cb[(base + d0 + 0) * S_ + s] = f2bf(acc[i][0] + bb.x);
      Cb[(base + d0 + 1) * S_ + s] = f2bf(acc[i][1] + bb.y);
      Cb[(base + d0 + 2) * S_ + s] = f2bf(acc[i][2] + bb.z);
      Cb[(base + d0 + 3) * S_ + s] = f2bf(acc[i][3] + bb.w);
    }
  }
}

// ---------------------------------------------------------------------------
// MFMA flash-style attention. grid (S/64, B*H), 256 threads = 4 waves.
// Each block: 64 q-rows; each wave: 16 q-rows. K-chunks of 64.
// Pass 1: QK^T (mfma 16x16x32 bf16) + online (m,l).  Pass 2: recompute,
// write normalized attn (fp32), P->LDS (bf16, per-wave tile), PV mfma.
// qt/kt: [bh][s][d] bf16 (q pre-scaled by 1/8).  vt: [bh][d][s] bf16.
// C-layout (verified m89): col = lane&15, row = (lane>>4)*4 + reg.
// A-layout: A[m=lane&15][k=quad*8+j];  B[k=quad*8+j][n=lane&15].
// ---------------------------------------------------------------------------
__global__ __launch_bounds__(256, 4) void attn_mfma(
    const unsigned short* __restrict__ qt, const unsigned short* __restrict__ kt,
    const unsigned short* __restrict__ vt, float* __restrict__ attn,
    float* __restrict__ ctx, const int* __restrict__ pmask)
{
  __shared__ unsigned short Qs[64][72];     // [q][d]    pad: rows 2-way only
  __shared__ unsigned short Ks[64][72];     // [k][d]
  __shared__ unsigned short Vs[64][72];     // [d][k]  (transposed tile)
  __shared__ unsigned short Ps[4][16][72];  // per-wave P tile [q][k]

  const int t    = threadIdx.x;
  const int w    = t >> 6;
  const int lane = t & 63;
  const int quad = lane >> 4;
  const int l16  = lane & 15;

  const int qblk = gridDim.x - 1 - blockIdx.x;   // heavy (causal) blocks first
  const int q0   = qblk * 64;
  const int bh   = blockIdx.y;
  const int isM  = pmask[0];
  const int kend = isM ? (q0 + 64) : S_;

  const unsigned short* qb = qt + (size_t)(bh * S_ + q0) * 64;
  const unsigned short* kb = kt + (size_t)bh * S_ * 64;
  const unsigned short* vb = vt + (size_t)bh * 64 * S_;

  // ---- stage Q tile (once) ----
#pragma unroll
  for (int i = 0; i < 2; ++i) {
    int idx = t + i * 256;
    int r = idx >> 3, c = (idx & 7) << 3;
    *(uint4*)&Qs[r][c] = *(const uint4*)&qb[(size_t)r * 64 + c];
  }
  __syncthreads();
  const bf16x8 qa0 = *(const bf16x8*)&Qs[w * 16 + l16][quad * 8];
  const bf16x8 qa1 = *(const bf16x8*)&Qs[w * 16 + l16][32 + quad * 8];

  float mrow[4] = {-1e30f, -1e30f, -1e30f, -1e30f};
  float lrow[4] = {0.f, 0.f, 0.f, 0.f};

  // ---------------- pass 1: stats ----------------
  for (int kc = 0; kc < kend; kc += 64) {
    __syncthreads();
#pragma unroll
    for (int i = 0; i < 2; ++i) {
      int idx = t + i * 256;
      int r = idx >> 3, c = (idx & 7) << 3;
      *(uint4*)&Ks[r][c] = *(const uint4*)&kb[(size_t)(kc + r) * 64 + c];
    }
    __syncthreads();

    f32x4 s[4];
#pragma unroll
    for (int j = 0; j < 4; ++j) {
      bf16x8 b0 = *(const bf16x8*)&Ks[j * 16 + l16][quad * 8];
      bf16x8 b1 = *(const bf16x8*)&Ks[j * 16 + l16][32 + quad * 8];
      f32x4 c0 = {0.f, 0.f, 0.f, 0.f};
      c0 = __builtin_amdgcn_mfma_f32_16x16x32_bf16(qa0, b0, c0, 0, 0, 0);
      c0 = __builtin_amdgcn_mfma_f32_16x16x32_bf16(qa1, b1, c0, 0, 0, 0);
      s[j] = c0;
    }
    if (isM && kc + 64 > q0) {
#pragma unroll
      for (int j = 0; j < 4; ++j) {
        int col = kc + j * 16 + l16;
#pragma unroll
        for (int r = 0; r < 4; ++r)
          if (col > q0 + w * 16 + quad * 4 + r) s[j][r] = -1e30f;
      }
    }
#pragma unroll
    for (int r = 0; r < 4; ++r) {
      float cm = fmaxf(fmaxf(s[0][r], s[1][r]), fmaxf(s[2][r], s[3][r]));
      cm = fmaxf(cm, __shfl_xor(cm, 1, 16));
      cm = fmaxf(cm, __shfl_xor(cm, 2, 16));
      cm = fmaxf(cm, __shfl_xor(cm, 4, 16));
      cm = fmaxf(cm, __shfl_xor(cm, 8, 16));
      float mn = fmaxf(mrow[r], cm);
      float cs = __expf(s[0][r] - mn) + __expf(s[1][r] - mn) +
                 __expf(s[2][r] - mn) + __expf(s[3][r] - mn);
      cs += __shfl_xor(cs, 1, 16);
      cs += __shfl_xor(cs, 2, 16);
      cs += __shfl_xor(cs, 4, 16);
      cs += __shfl_xor(cs, 8, 16);
      lrow[r] = lrow[r] * __expf(mrow[r] - mn) + cs;
      mrow[r] = mn;
    }
  }

  float invl[4];
#pragma unroll
  for (int r = 0; r < 4; ++r) invl[r] = 1.f / lrow[r];

  // ---------------- pass 2: attn write + PV ----------------
  f32x4 oacc[4];
#pragma unroll
  for (int n = 0; n < 4; ++n) oacc[n] = (f32x4){0.f, 0.f, 0.f, 0.f};

  for (int kc = 0; kc < kend; kc += 64) {
    __syncthreads();
#pragma unroll
    for (int i = 0; i < 2; ++i) {
      int idx = t + i * 256;
      int r = idx >> 3, c = (idx & 7) << 3;
      *(uint4*)&Ks[r][c] = *(const uint4*)&kb[(size_t)(kc + r) * 64 + c];
      *(uint4*)&Vs[r][c] = *(const uint4*)&vb[(size_t)r * S_ + kc + c];
    }
    __syncthreads();

    f32x4 s[4];
#pragma unroll
    for (int j = 0; j < 4; ++j) {
      bf16x8 b0 = *(const bf16x8*)&Ks[j * 16 + l16][quad * 8];
      bf16x8 b1 = *(const bf16x8*)&Ks[j * 16 + l16][32 + quad * 8];
      f32x4 c0 = {0.f, 0.f, 0.f, 0.f};
      c0 = __builtin_amdgcn_mfma_f32_16x16x32_bf16(qa0, b0, c0, 0, 0, 0);
      c0 = __builtin_amdgcn_mfma_f32_16x16x32_bf16(qa1, b1, c0, 0, 0, 0);
      s[j] = c0;
    }
    if (isM && kc + 64 > q0) {
#pragma unroll
      for (int j = 0; j < 4; ++j) {
        int col = kc + j * 16 + l16;
#pragma unroll
        for (int r = 0; r < 4; ++r)
          if (col > q0 + w * 16 + quad * 4 + r) s[j][r] = -1e30f;
      }
    }

    // p = exp(s - m) / l ; write attn + per-wave LDS P tile
#pragma unroll
    for (int j = 0; j < 4; ++j) {
#pragma unroll
      for (int r = 0; r < 4; ++r) {
        float p = __expf(s[j][r] - mrow[r]) * invl[r];
        attn[((size_t)bh * S_ + q0 + w * 16 + quad * 4 + r) * S_ + kc + j * 16 + l16] = p;
        Ps[w][quad * 4 + r][j * 16 + l16] = f2bf(p);
      }
    }
    // per-wave LDS dependency (write->read, same wave): lgkmcnt handles it

    bf16x8 pa0 = *(const bf16x8*)&Ps[w][l16][quad * 8];
    bf16x8 pa1 = *(const bf16x8*)&Ps[w][l16][32 + quad * 8];
#pragma unroll
    for (int n = 0; n < 4; ++n) {
      bf16x8 v0 = *(const bf16x8*)&Vs[n * 16 + l16][quad * 8];
      bf16x8 v1 = *(const bf16x8*)&Vs[n * 16 + l16][32 + quad * 8];
      oacc[n] = __builtin_amdgcn_mfma_f32_16x16x32_bf16(pa0, v0, oacc[n], 0, 0, 0);
      oacc[n] = __builtin_amdgcn_mfma_f32_16x16x32_bf16(pa1, v1, oacc[n], 0, 0, 0);
    }
  }

  // zero-fill fully-masked tail (d_out poisoned each launch)
  if (isM) {
    int row = q0 + (t >> 2);
    float4 z = {0.f, 0.f, 0.f, 0.f};
    for (int c = kend + ((t & 3) << 2); c < S_; c += 16)
      *(float4*)&attn[((size_t)bh * S_ + row) * S_ + c] = z;
  }

  // store O tile -> ctx[b*s][h*64+d]  (fp32)
  const int b = bh >> 4, h = bh & 15;
#pragma unroll
  for (int r = 0; r < 4; ++r) {
    int row = q0 + w * 16 + quad * 4 + r;
    size_t base = ((size_t)(b * S_ + row)) * HD_ + h * 64 + l16;
#pragma unroll
    for (int n = 0; n < 4; ++n)
      ctx[base + n * 16] = oacc[n][r];
  }
}

// ---------------------------------------------------------------------------
// In-place residual + LayerNorm over last dim (1024). One block per row.
// ---------------------------------------------------------------------------
__global__ __launch_bounds__(256) void ln_kernel(
    float* __restrict__ y, const float* __restrict__ resid)
{
  __shared__ float red[8];
  const int row = blockIdx.x, t = threadIdx.x;
  const size_t base = (size_t)row * 1024 + (t << 2);
  float4 x = *(float4*)&y[base];
  float4 r = *(const float4*)&resid[base];
  x.x += r.x; x.y += r.y; x.z += r.z; x.w += r.w;
  float sum = x.x + x.y + x.z + x.w;
  float ss  = x.x*x.x + x.y*x.y + x.z*x.z + x.w*x.w;
#pragma unroll
  for (int off = 1; off < 64; off <<= 1) {
    sum += __shfl_xor(sum, off);
    ss  += __shfl_xor(ss,  off);
  }
  const int wid = t >> 6;
  if ((t & 63) == 0) { red[wid] = sum; red[4 + wid] = ss; }
  __syncthreads();
  sum = red[0] + red[1] + red[2] + red[3];
  ss  = red[4] + red[5] + red[6] + red[7];
  const float mu  = sum * (1.f / 1024.f);
  const float var = ss * (1.f / 1024.f) - mu * mu;
  const float rs  = rsqrtf(var + LN_EPS);
  x.x = (x.x - mu) * rs; x.y = (x.y - mu) * rs;
  x.z = (x.z - mu) * rs; x.w = (x.w - mu) * rs;
  *(float4*)&y[base] = x;
}

// ---------------------------------------------------------------------------
extern "C" void kernel_launch(void* const* d_in, const int* in_sizes, int n_in,
                              void* d_out, int out_size, void* d_ws, size_t ws_size,
                              hipStream_t stream) {
  const float* q    = (const float*)d_in[0];
  const float* k    = (const float*)d_in[1];
  const float* v    = (const float*)d_in[2];
  const float* Wq   = (const float*)d_in[3];
  const float* bq   = (const float*)d_in[4];
  const float* Wk   = (const float*)d_in[5];
  const float* bk   = (const float*)d_in[6];
  const float* Wv   = (const float*)d_in[7];
  const float* bv   = (const float*)d_in[8];
  const float* Wo   = (const float*)d_in[9];
  const float* bo   = (const float*)d_in[10];
  const int*   mask = (const int*)d_in[11];

  float* outs = (float*)d_out;                         // [B*S, E]
  float* attn = outs + (size_t)BS_ * E_;               // [B, H, S, S]

  const size_t NBHSD = (size_t)BS_ * HD_;              // 4M elements
  unsigned short* qt = (unsigned short*)d_ws;          // bf16 [bh][s][d]
  unsigned short* kt = qt + NBHSD;
  unsigned short* vt = kt + NBHSD;                     // bf16 [bh][d][s]
  float* ctx = (float*)(vt + NBHSD);                   // fp32 [b*s][h*d]

  const dim3 gg(HD_ / 64, BS_ / 64);                   // (16, 64)
  gemm_bias_k<1><<<gg, 256, 0, stream>>>(q, Wq, bq, nullptr, qt, BS_, HD_, E_, 0.125f);
  gemm_bias_k<1><<<gg, 256, 0, stream>>>(k, Wk, bk, nullptr, kt, BS_, HD_, E_, 1.0f);
  gemm_bias_k<2><<<gg, 256, 0, stream>>>(v, Wv, bv, nullptr, vt, BS_, HD_, E_, 1.0f);

  attn_mfma<<<dim3(S_ / 64, B_ * H_), 256, 0, stream>>>(qt, kt, vt, attn, ctx, mask);

  gemm_bias_k<0><<<dim3(E_ / 64, BS_ / 64), 256, 0, stream>>>(ctx, Wo, bo, outs, nullptr, BS_, E_, HD_, 1.0f);
  ln_kernel<<<BS_, 256, 0, stream>>>(outs, q);
}